// Round 4
// baseline (644.050 us; speedup 1.0000x reference)
//
#include <hip/hip_runtime.h>
#include <hip/hip_bf16.h>
#include <hip/hip_cooperative_groups.h>

namespace cg = cooperative_groups;

#define HWs 25600   // 160*160
#define NB 16       // batches
#define NC 128      // channels
#define NS 256      // selected per batch
#define NN 4096     // NB*NS total rows
#define TOTF4 13107200   // NB*NC*HWs/4 float4 elements of z
#define CA 7340032       // float4s copied in phase A (~56%)

typedef __attribute__((ext_vector_type(8))) short bf16x8;
typedef __attribute__((ext_vector_type(4))) float f32x4;
typedef __attribute__((ext_vector_type(4))) int i32x4;
typedef unsigned long long u64;

union SMem {
  struct { int hist[256]; int scan_s[256]; int scan_eq[256]; int sel_s[256]; int bc[2]; } a;
  struct { ushort tA[64 * 128]; ushort tB[64 * 128]; u64 rowbits[64]; } b;   // 33280 B
  struct { float aggT[16 * 128]; } c;
};

// ==================== cooperative mega-kernel ====================
__global__ __launch_bounds__(256, 4) void mega_kernel(
    const float* __restrict__ z, const float* __restrict__ score,
    const float* __restrict__ Wg, const float* __restrict__ bg,
    float* __restrict__ out, int* __restrict__ sel,
    float* __restrict__ feats, ushort* __restrict__ nfb,
    u64* __restrict__ adj) {
  __shared__ __align__(16) SMem sm;
  cg::grid_group grid = cg::this_grid();
  const int tid = threadIdx.x;
  const int bid = blockIdx.x;
  const int nb = gridDim.x;
  const float4* z4 = (const float4*)z;
  float4* out4 = (float4*)out;

  // ---------------- Phase A: topk+gather (blocks 0..15) || copy slice A ----------------
  if (bid < NB) {
    int b = bid;
    const float* sc = score + (size_t)b * HWs;
    int* hist = sm.a.hist; int* scan_s = sm.a.scan_s; int* scan_eq = sm.a.scan_eq;
    int* sel_s = sm.a.sel_s; int* bc = sm.a.bc;

    unsigned prefix = 0; int k = NS;
    for (int d = 3; d >= 0; --d) {
      int sh = d * 8;
      hist[tid] = 0; __syncthreads();
      unsigned maskHigh = (d == 3) ? 0u : (0xFFFFFFFFu << (sh + 8));
      for (int i = tid; i < HWs; i += 256) {
        unsigned v = __float_as_uint(sc[i]);
        if ((v & maskHigh) == prefix) atomicAdd(&hist[(v >> sh) & 255], 1);
      }
      __syncthreads();
      int val = hist[255 - tid];
      scan_s[tid] = val; __syncthreads();
      for (int off = 1; off < 256; off <<= 1) {
        int a = (tid >= off) ? scan_s[tid - off] : 0;
        __syncthreads();
        scan_s[tid] += a; __syncthreads();
      }
      int q = 255 - tid;
      int Sq = scan_s[tid];
      int before = Sq - hist[q];
      if (before < k && k <= Sq) { bc[0] = q; bc[1] = k - before; }
      __syncthreads();
      prefix |= ((unsigned)bc[0]) << sh;
      k = bc[1];
      __syncthreads();
    }
    unsigned t = prefix;
    // stable compaction: all v>t plus first (NS-#gt) v==t by index
    int cstart = tid * 100, cend = cstart + 100;
    int cgt = 0, ceq = 0;
    for (int i = cstart; i < cend; ++i) {
      unsigned v = __float_as_uint(sc[i]);
      cgt += (v > t) ? 1 : 0;
      ceq += (v == t) ? 1 : 0;
    }
    scan_s[tid] = cgt; scan_eq[tid] = ceq; __syncthreads();
    for (int off = 1; off < 256; off <<= 1) {
      int ag = (tid >= off) ? scan_s[tid - off] : 0;
      int ae = (tid >= off) ? scan_eq[tid - off] : 0;
      __syncthreads();
      scan_s[tid] += ag; scan_eq[tid] += ae; __syncthreads();
    }
    int total_gt = scan_s[255];
    int need = NS - total_gt;
    int g = scan_s[tid] - cgt;
    int e = scan_eq[tid] - ceq;
    for (int i = cstart; i < cend; ++i) {
      unsigned v = __float_as_uint(sc[i]);
      if (v > t) { sel_s[g] = i; sel[b * NS + g] = i; ++g; }
      else if (v == t) {
        if (e < need) { sel_s[total_gt + e] = i; sel[b * NS + total_gt + e] = i; }
        ++e;
      }
    }
    __syncthreads();
    // gather + row-normalize (wave per row)
    int w = tid >> 6, lane = tid & 63;
    for (int s = w; s < NS; s += 4) {
      int idx = sel_s[s];
      const float* zb = z + ((size_t)b * NC) * HWs + idx;
      float v0 = zb[(size_t)lane * HWs];
      float v1 = zb[(size_t)(lane + 64) * HWs];
      float ss = v0 * v0 + v1 * v1;
      #pragma unroll
      for (int off = 32; off; off >>= 1) ss += __shfl_xor(ss, off);
      float denom = fmaxf(sqrtf(ss), 1e-12f);
      int row = b * NS + s;
      feats[row * NC + lane] = v0;
      feats[row * NC + lane + 64] = v1;
      __hip_bfloat16 h0 = __float2bfloat16(v0 / denom);
      __hip_bfloat16 h1 = __float2bfloat16(v1 / denom);
      nfb[row * NC + lane] = *reinterpret_cast<ushort*>(&h0);
      nfb[row * NC + lane + 64] = *reinterpret_cast<ushort*>(&h1);
    }
  } else {
    for (size_t i = (size_t)(bid - NB) * 256 + tid; i < (size_t)CA; i += (size_t)(nb - NB) * 256)
      out4[i] = z4[i];
  }
  __threadfence();
  grid.sync();

  // ---------------- Phase B: sim MFMA tiles (grid-stride) + copy slice B ----------------
  {
    ushort* tA = sm.b.tA; ushort* tB = sm.b.tB; u64* rowbits = sm.b.rowbits;
    for (int tix = bid; tix < 4096; tix += nb) {
      int I0 = (tix & 63) * 64, J0 = (tix >> 6) * 64;
      if (tid < 64) rowbits[tid] = 0ull;
      for (int f = tid; f < 1024; f += 256) {
        int r = f >> 4, c = f & 15;
        int scnk = c ^ (r & 7);
        *(i32x4*)&tA[r * 128 + scnk * 8] = *(const i32x4*)(nfb + (size_t)(I0 + r) * NC + c * 8);
        *(i32x4*)&tB[r * 128 + scnk * 8] = *(const i32x4*)(nfb + (size_t)(J0 + r) * NC + c * 8);
      }
      __syncthreads();
      int w = tid >> 6, l = tid & 63;
      int r = l & 15, kg = l >> 4;
      f32x4 acc[4] = {{0.f, 0.f, 0.f, 0.f}, {0.f, 0.f, 0.f, 0.f},
                      {0.f, 0.f, 0.f, 0.f}, {0.f, 0.f, 0.f, 0.f}};
      int Ar = 16 * w + r;
      #pragma unroll
      for (int kk = 0; kk < 4; ++kk) {
        int chunkA = (kk * 4 + kg) ^ (Ar & 7);
        bf16x8 a = *(bf16x8*)&tA[Ar * 128 + chunkA * 8];
        #pragma unroll
        for (int j = 0; j < 4; ++j) {
          int Bc = 16 * j + r;
          int chunkB = (kk * 4 + kg) ^ (Bc & 7);
          bf16x8 bf = *(bf16x8*)&tB[Bc * 128 + chunkB * 8];
          acc[j] = __builtin_amdgcn_mfma_f32_16x16x32_bf16(a, bf, acc[j], 0, 0, 0);
        }
      }
      #pragma unroll
      for (int q = 0; q < 4; ++q) {
        u64 m = 0ull;
        #pragma unroll
        for (int j = 0; j < 4; ++j) {
          float simv = acc[j][q];
          if ((1.0f - simv) * 0.5f < 0.2f) m |= 1ull << (16 * j + (l & 15));
        }
        if (m) atomicOr(&rowbits[16 * w + (l >> 4) * 4 + q], m);
      }
      __syncthreads();
      if (tid < 64) adj[(size_t)(I0 + tid) * 64 + (tix >> 6)] = rowbits[tid];
    }
    // copy slice B (finishes ALL copying before scatter phase)
    for (size_t i = (size_t)CA + (size_t)bid * 256 + tid; i < (size_t)TOTF4; i += (size_t)nb * 256)
      out4[i] = z4[i];
  }
  __threadfence();
  grid.sync();

  // ---------------- Phase C: deg-on-fly + sparse agg + GEMM + scatter (blocks 0..255) ----------------
  if (bid < 256) {
    float* aggT = sm.c.aggT;
    int r0 = bid * 16;
    int w = tid >> 6, lane = tid & 63;
    for (int rr = 0; rr < 4; ++rr) {
      int lrow = w * 4 + rr;
      int row = r0 + lrow;
      u64 mw = adj[(size_t)row * 64 + lane];
      int ctot = __popcll(mw);
      #pragma unroll
      for (int off = 32; off; off >>= 1) ctot += __shfl_xor(ctot, off);
      float dinv_i = 1.0f / sqrtf(fmaxf((float)ctot, 1.0f));
      float acc0 = 0.f, acc1 = 0.f;
      for (int wi = 0; wi < 64; ++wi) {
        u64 w64 = __shfl((long long)mw, wi);
        while (w64) {
          int bit = __builtin_ctzll(w64);
          w64 &= w64 - 1;
          int j = wi * 64 + bit;            // ascending j (deterministic order)
          u64 jm = adj[(size_t)j * 64 + lane];
          int cj = __popcll(jm);
          #pragma unroll
          for (int off = 32; off; off >>= 1) cj += __shfl_xor(cj, off);
          float dj = 1.0f / sqrtf(fmaxf((float)cj, 1.0f));
          acc0 += dj * feats[(size_t)j * NC + lane];
          acc1 += dj * feats[(size_t)j * NC + lane + 64];
        }
      }
      aggT[lrow * NC + lane] = dinv_i * acc0;
      aggT[lrow * NC + lane + 64] = dinv_i * acc1;
    }
    __syncthreads();
    int cp = tid & 127, rsub = tid >> 7;
    float accq[8];
    float bb = bg[cp];
    #pragma unroll
    for (int q = 0; q < 8; ++q) accq[q] = bb;
    #pragma unroll 4
    for (int c = 0; c < NC; ++c) {
      float wv = Wg[c * NC + cp];
      #pragma unroll
      for (int q = 0; q < 8; ++q) accq[q] += aggT[(rsub + 2 * q) * NC + c] * wv;
    }
    #pragma unroll
    for (int q = 0; q < 8; ++q) {
      int row = r0 + rsub + 2 * q;
      int b = row >> 8;
      int idx = sel[row];
      out[((size_t)b * NC + cp) * HWs + idx] = accq[q];
    }
  }
}

// ==================== fallback pipeline (round-3, verified) ====================
__global__ __launch_bounds__(256) void copy_kernel(const float4* __restrict__ in,
                                                   float4* __restrict__ out, int n4) {
  int i = blockIdx.x * blockDim.x + threadIdx.x;
  int stride = gridDim.x * blockDim.x;
  for (; i < n4; i += stride) out[i] = in[i];
}

__global__ __launch_bounds__(256) void topk_kernel(const float* __restrict__ score,
                                                   int* __restrict__ sel) {
  __shared__ unsigned int vals[HWs];
  __shared__ int hist[256];
  __shared__ int scan_s[256];
  __shared__ int scan_eq[256];
  __shared__ int bc_dig, bc_k;
  int b = blockIdx.x;
  int tid = threadIdx.x;
  const float* sc = score + (size_t)b * HWs;
  for (int i = tid; i < HWs; i += 256) vals[i] = __float_as_uint(sc[i]);
  __syncthreads();
  unsigned prefix = 0; int k = NS;
  for (int d = 3; d >= 0; --d) {
    int sh = d * 8;
    hist[tid] = 0; __syncthreads();
    unsigned maskHigh = (d == 3) ? 0u : (0xFFFFFFFFu << (sh + 8));
    for (int i = tid; i < HWs; i += 256) {
      unsigned v = vals[i];
      if ((v & maskHigh) == prefix) atomicAdd(&hist[(v >> sh) & 255], 1);
    }
    __syncthreads();
    int v = hist[255 - tid];
    scan_s[tid] = v; __syncthreads();
    for (int off = 1; off < 256; off <<= 1) {
      int a = (tid >= off) ? scan_s[tid - off] : 0;
      __syncthreads();
      scan_s[tid] += a; __syncthreads();
    }
    int q = 255 - tid;
    int Sq = scan_s[tid];
    int before = Sq - hist[q];
    if (before < k && k <= Sq) { bc_dig = q; bc_k = k - before; }
    __syncthreads();
    prefix |= ((unsigned)bc_dig) << sh;
    k = bc_k;
    __syncthreads();
  }
  unsigned t = prefix;
  int cstart = tid * 100, cend = cstart + 100;
  int cgt = 0, ceq = 0;
  for (int i = cstart; i < cend; ++i) {
    unsigned v = vals[i];
    cgt += (v > t) ? 1 : 0;
    ceq += (v == t) ? 1 : 0;
  }
  scan_s[tid] = cgt; scan_eq[tid] = ceq; __syncthreads();
  for (int off = 1; off < 256; off <<= 1) {
    int ag = (tid >= off) ? scan_s[tid - off] : 0;
    int ae = (tid >= off) ? scan_eq[tid - off] : 0;
    __syncthreads();
    scan_s[tid] += ag; scan_eq[tid] += ae; __syncthreads();
  }
  int total_gt = scan_s[255];
  int need = NS - total_gt;
  int g = scan_s[tid] - cgt;
  int e = scan_eq[tid] - ceq;
  for (int i = cstart; i < cend; ++i) {
    unsigned v = vals[i];
    if (v > t) { sel[b * NS + g] = i; ++g; }
    else if (v == t) { if (e < need) sel[b * NS + total_gt + e] = i; ++e; }
  }
}

__global__ __launch_bounds__(256) void gather_norm_kernel(const float* __restrict__ z,
                                                          const int* __restrict__ sel,
                                                          float* __restrict__ feats,
                                                          ushort* __restrict__ nfb) {
  int row = blockIdx.x * 4 + (threadIdx.x >> 6);
  int lane = threadIdx.x & 63;
  int b = row >> 8;
  int idx = sel[row];
  const float* zb = z + (size_t)b * NC * HWs + idx;
  float v0 = zb[(size_t)lane * HWs];
  float v1 = zb[(size_t)(lane + 64) * HWs];
  float ss = v0 * v0 + v1 * v1;
  #pragma unroll
  for (int off = 32; off; off >>= 1) ss += __shfl_xor(ss, off);
  float denom = fmaxf(sqrtf(ss), 1e-12f);
  feats[row * NC + lane] = v0;
  feats[row * NC + lane + 64] = v1;
  __hip_bfloat16 h0 = __float2bfloat16(v0 / denom);
  __hip_bfloat16 h1 = __float2bfloat16(v1 / denom);
  nfb[row * NC + lane] = *reinterpret_cast<ushort*>(&h0);
  nfb[row * NC + lane + 64] = *reinterpret_cast<ushort*>(&h1);
}

__global__ __launch_bounds__(256) void sim_kernel(const ushort* __restrict__ nfb,
                                                  u64* __restrict__ adj) {
  __shared__ __align__(16) ushort tA[64 * 128];
  __shared__ __align__(16) ushort tB[64 * 128];
  __shared__ u64 rowbits[64];
  int I0 = blockIdx.x * 64, J0 = blockIdx.y * 64;
  int tid = threadIdx.x;
  if (tid < 64) rowbits[tid] = 0ull;
  for (int f = tid; f < 1024; f += 256) {
    int r = f >> 4, c = f & 15;
    int scnk = c ^ (r & 7);
    *(i32x4*)&tA[r * 128 + scnk * 8] = *(const i32x4*)(nfb + (size_t)(I0 + r) * NC + c * 8);
    *(i32x4*)&tB[r * 128 + scnk * 8] = *(const i32x4*)(nfb + (size_t)(J0 + r) * NC + c * 8);
  }
  __syncthreads();
  int w = tid >> 6, l = tid & 63;
  int r = l & 15, kg = l >> 4;
  f32x4 acc[4] = {{0.f, 0.f, 0.f, 0.f}, {0.f, 0.f, 0.f, 0.f},
                  {0.f, 0.f, 0.f, 0.f}, {0.f, 0.f, 0.f, 0.f}};
  int Ar = 16 * w + r;
  #pragma unroll
  for (int kk = 0; kk < 4; ++kk) {
    int chunkA = (kk * 4 + kg) ^ (Ar & 7);
    bf16x8 a = *(bf16x8*)&tA[Ar * 128 + chunkA * 8];
    #pragma unroll
    for (int j = 0; j < 4; ++j) {
      int Bc = 16 * j + r;
      int chunkB = (kk * 4 + kg) ^ (Bc & 7);
      bf16x8 bf = *(bf16x8*)&tB[Bc * 128 + chunkB * 8];
      acc[j] = __builtin_amdgcn_mfma_f32_16x16x32_bf16(a, bf, acc[j], 0, 0, 0);
    }
  }
  #pragma unroll
  for (int q = 0; q < 4; ++q) {
    u64 m = 0ull;
    #pragma unroll
    for (int j = 0; j < 4; ++j) {
      float simv = acc[j][q];
      if ((1.0f - simv) * 0.5f < 0.2f) m |= 1ull << (16 * j + (l & 15));
    }
    if (m) atomicOr(&rowbits[16 * w + (l >> 4) * 4 + q], m);
  }
  __syncthreads();
  if (tid < 64) adj[(size_t)(I0 + tid) * 64 + blockIdx.y] = rowbits[tid];
}

__global__ __launch_bounds__(256) void deg_kernel(const u64* __restrict__ adj,
                                                  float* __restrict__ dinv) {
  int row = blockIdx.x * 4 + (threadIdx.x >> 6);
  int lane = threadIdx.x & 63;
  int cnt = __popcll(adj[(size_t)row * 64 + lane]);
  #pragma unroll
  for (int off = 32; off; off >>= 1) cnt += __shfl_xor(cnt, off);
  if (lane == 0) dinv[row] = 1.0f / sqrtf(fmaxf((float)cnt, 1.0f));
}

__global__ __launch_bounds__(128) void agg_kernel(const u64* __restrict__ adj,
                                                  const float* __restrict__ feats,
                                                  const float* __restrict__ dinv,
                                                  float* __restrict__ agg) {
  __shared__ int list[NN];
  __shared__ int cnt_s;
  int row = blockIdx.x;
  int tid = threadIdx.x;
  if (tid < 64) {
    u64 w = adj[(size_t)row * 64 + tid];
    int c = __popcll(w);
    int x = c;
    #pragma unroll
    for (int off = 1; off < 64; off <<= 1) {
      int y = __shfl_up(x, off);
      if (tid >= off) x += y;
    }
    int pos = x - c;
    while (w) {
      int bit = __builtin_ctzll(w);
      list[pos++] = tid * 64 + bit;
      w &= w - 1;
    }
    if (tid == 63) cnt_s = x;
  }
  __syncthreads();
  int cnt = cnt_s;
  float di = dinv[row];
  float acc = 0.0f;
  for (int e2 = 0; e2 < cnt; ++e2) {
    int j = list[e2];
    acc += dinv[j] * feats[(size_t)j * NC + tid];
  }
  agg[(size_t)row * NC + tid] = di * acc;
}

__global__ __launch_bounds__(256) void out_kernel(const float* __restrict__ agg,
                                                  const float* __restrict__ Wg,
                                                  const float* __restrict__ bias,
                                                  const int* __restrict__ sel,
                                                  float* __restrict__ out) {
  __shared__ __align__(16) float Wt[NC * 132];
  __shared__ __align__(16) float aggT[16 * 132];
  int tid = threadIdx.x;
  int r0 = blockIdx.x * 16;
  for (int f = tid; f < NC * NC; f += 256) {
    int c = f >> 7, cp = f & 127;
    Wt[cp * 132 + c] = Wg[f];
  }
  for (int f = tid; f < 16 * NC; f += 256) {
    int r = f >> 7, c = f & 127;
    aggT[r * 132 + c] = agg[(size_t)(r0 + r) * NC + c];
  }
  __syncthreads();
  int cp = tid & 127;
  int rsub = tid >> 7;
  float acc[8];
  float bb = bias[cp];
  #pragma unroll
  for (int q = 0; q < 8; ++q) acc[q] = bb;
  for (int c4 = 0; c4 < 32; ++c4) {
    float4 w4 = *(const float4*)&Wt[cp * 132 + c4 * 4];
    #pragma unroll
    for (int q = 0; q < 8; ++q) {
      float4 a4 = *(const float4*)&aggT[(rsub + 2 * q) * 132 + c4 * 4];
      acc[q] += a4.x * w4.x + a4.y * w4.y + a4.z * w4.z + a4.w * w4.w;
    }
  }
  #pragma unroll
  for (int q = 0; q < 8; ++q) {
    int row = r0 + rsub + 2 * q;
    int batch = row >> 8;
    int idx = sel[row];
    out[(size_t)(batch * NC + cp) * HWs + idx] = acc[q];
  }
}

extern "C" void kernel_launch(void* const* d_in, const int* in_sizes, int n_in,
                              void* d_out, int out_size, void* d_ws, size_t ws_size,
                              hipStream_t stream) {
  const float* z     = (const float*)d_in[0];
  const float* score = (const float*)d_in[1];
  const float* Wg    = (const float*)d_in[2];
  const float* bg    = (const float*)d_in[3];
  float* out = (float*)d_out;

  char* ws = (char*)d_ws;
  size_t off = 0;
  auto alloc = [&](size_t bytes) {
    void* p = ws + off;
    off = (off + bytes + 255) & ~(size_t)255;
    return p;
  };
  int* sel    = (int*)alloc(NN * sizeof(int));
  float* feats = (float*)alloc((size_t)NN * NC * sizeof(float));
  ushort* nfb  = (ushort*)alloc((size_t)NN * NC * sizeof(ushort));
  u64* adj     = (u64*)alloc((size_t)NN * 64 * sizeof(u64));
  float* dinv  = (float*)alloc(NN * sizeof(float));       // fallback only
  float* agg   = (float*)alloc((size_t)NN * NC * sizeof(float));  // fallback only

  int maxPerCU = 0;
  hipOccupancyMaxActiveBlocksPerMultiprocessor(&maxPerCU, mega_kernel, 256, 0);
  int nb = maxPerCU * 256;   // 256 CUs on MI355X
  if (nb > 1024) nb = 1024;
  if (nb < 256) nb = 256;    // phase C needs 256 blocks; occupancy math guarantees >=4/CU

  const float* zc = z; const float* scc = score; const float* wgc = Wg; const float* bgc = bg;
  float* outc = out;
  void* args[] = {(void*)&zc, (void*)&scc, (void*)&wgc, (void*)&bgc,
                  (void*)&outc, (void*)&sel, (void*)&feats, (void*)&nfb, (void*)&adj};
  hipError_t err = hipLaunchCooperativeKernel((void*)mega_kernel, dim3(nb), dim3(256),
                                              args, 0, stream);
  if (err != hipSuccess) {
    // fallback: verified round-3 pipeline
    copy_kernel<<<2048, 256, 0, stream>>>((const float4*)z, (float4*)out, TOTF4);
    topk_kernel<<<NB, 256, 0, stream>>>(score, sel);
    gather_norm_kernel<<<NN / 4, 256, 0, stream>>>(z, sel, feats, nfb);
    sim_kernel<<<dim3(64, 64), 256, 0, stream>>>(nfb, adj);
    deg_kernel<<<NN / 4, 256, 0, stream>>>(adj, dinv);
    agg_kernel<<<NN, 128, 0, stream>>>(adj, feats, dinv, agg);
    out_kernel<<<NN / 16, 256, 0, stream>>>(agg, Wg, bg, sel, out);
  }
}

// Round 5
// 305.518 us; speedup vs baseline: 2.1081x; 2.1081x over previous
//
#include <hip/hip_runtime.h>
#include <hip/hip_bf16.h>

#define HWs 25600   // 160*160
#define NB 16       // batches
#define NC 128      // channels
#define NS 256      // selected per batch
#define NN 4096     // NB*NS total rows
#define N4 13107200          // NB*NC*HWs/4 float4 elements of z
#define K1_GRID 4096
#define CPB (K1_GRID - NB)   // 4080 copy blocks
#define CSTRIDE (CPB * 256)  // 1044480 copy threads
#define CTAIL (N4 - 12 * CSTRIDE)  // 573440

typedef __attribute__((ext_vector_type(8))) short bf16x8;
typedef __attribute__((ext_vector_type(4))) float f32x4;
typedef __attribute__((ext_vector_type(4))) int i32x4;
typedef unsigned long long u64;

// ==================== K1: {topk+gather+norm | bulk copy} ====================
// Blocks 0..15: exact per-batch top-256 (radix select on f32 bits, score read
// from global/L2 -- no big LDS so copy blocks keep full occupancy), then
// fused gather + row-normalize. Blocks 16+: 12-deep unrolled z->out copy.
__global__ __launch_bounds__(256, 4) void k1_kernel(
    const float* __restrict__ z, const float* __restrict__ score,
    float* __restrict__ out, int* __restrict__ sel,
    float* __restrict__ feats, ushort* __restrict__ nfb) {
  const int tid = threadIdx.x;
  const int bid = blockIdx.x;

  if (bid >= NB) {
    // ---- copy slice: 12 strided float4 + conditional tail, all loads issued first ----
    const float4* zz = (const float4*)z;
    float4* oo = (float4*)out;
    int i0 = (bid - NB) * 256 + tid;
    float4 v[12];
    #pragma unroll
    for (int k = 0; k < 12; ++k) v[k] = zz[(size_t)i0 + (size_t)k * CSTRIDE];
    bool tail = i0 < CTAIL;
    float4 vt;
    if (tail) vt = zz[(size_t)i0 + (size_t)12 * CSTRIDE];
    #pragma unroll
    for (int k = 0; k < 12; ++k) oo[(size_t)i0 + (size_t)k * CSTRIDE] = v[k];
    if (tail) oo[(size_t)i0 + (size_t)12 * CSTRIDE] = vt;
    return;
  }

  // ---- topk for batch b = bid ----
  __shared__ int hist[256];
  __shared__ int scan_s[256];
  __shared__ int scan_eq[256];
  __shared__ int sel_s[256];
  __shared__ int bc[2];
  int b = bid;
  const float* sc = score + (size_t)b * HWs;

  unsigned prefix = 0; int k = NS;
  for (int d = 3; d >= 0; --d) {
    int sh = d * 8;
    hist[tid] = 0; __syncthreads();
    unsigned maskHigh = (d == 3) ? 0u : (0xFFFFFFFFu << (sh + 8));
    for (int i = tid; i < HWs; i += 256) {
      unsigned v = __float_as_uint(sc[i]);
      if ((v & maskHigh) == prefix) atomicAdd(&hist[(v >> sh) & 255], 1);
    }
    __syncthreads();
    int val = hist[255 - tid];
    scan_s[tid] = val; __syncthreads();
    for (int off = 1; off < 256; off <<= 1) {
      int a = (tid >= off) ? scan_s[tid - off] : 0;
      __syncthreads();
      scan_s[tid] += a; __syncthreads();
    }
    int q = 255 - tid;
    int Sq = scan_s[tid];          // count of elements with digit >= q (under prefix)
    int before = Sq - hist[q];     // count with digit > q
    if (before < k && k <= Sq) { bc[0] = q; bc[1] = k - before; }  // exactly one thread
    __syncthreads();
    prefix |= ((unsigned)bc[0]) << sh;
    k = bc[1];
    __syncthreads();
  }
  unsigned t = prefix;

  // stable compaction: all v > t, plus first (NS - #gt) elements v == t by index
  int cstart = tid * 100, cend = cstart + 100;
  int cgt = 0, ceq = 0;
  for (int i = cstart; i < cend; ++i) {
    unsigned v = __float_as_uint(sc[i]);
    cgt += (v > t) ? 1 : 0;
    ceq += (v == t) ? 1 : 0;
  }
  scan_s[tid] = cgt; scan_eq[tid] = ceq; __syncthreads();
  for (int off = 1; off < 256; off <<= 1) {
    int ag = (tid >= off) ? scan_s[tid - off] : 0;
    int ae = (tid >= off) ? scan_eq[tid - off] : 0;
    __syncthreads();
    scan_s[tid] += ag; scan_eq[tid] += ae; __syncthreads();
  }
  int total_gt = scan_s[255];
  int need = NS - total_gt;
  int g = scan_s[tid] - cgt;
  int e = scan_eq[tid] - ceq;
  for (int i = cstart; i < cend; ++i) {
    unsigned v = __float_as_uint(sc[i]);
    if (v > t) { sel_s[g] = i; sel[b * NS + g] = i; ++g; }
    else if (v == t) {
      if (e < need) { sel_s[total_gt + e] = i; sel[b * NS + total_gt + e] = i; }
      ++e;
    }
  }
  __syncthreads();

  // ---- fused gather + row-normalize (wave per row, 64 rows/wave) ----
  int w = tid >> 6, lane = tid & 63;
  for (int s = w; s < NS; s += 4) {
    int idx = sel_s[s];
    const float* zb = z + ((size_t)b * NC) * HWs + idx;
    float v0 = zb[(size_t)lane * HWs];
    float v1 = zb[(size_t)(lane + 64) * HWs];
    float ss = v0 * v0 + v1 * v1;
    #pragma unroll
    for (int off = 32; off; off >>= 1) ss += __shfl_xor(ss, off);
    float denom = fmaxf(sqrtf(ss), 1e-12f);
    int row = b * NS + s;
    feats[row * NC + lane] = v0;
    feats[row * NC + lane + 64] = v1;
    __hip_bfloat16 h0 = __float2bfloat16(v0 / denom);
    __hip_bfloat16 h1 = __float2bfloat16(v1 / denom);
    nfb[row * NC + lane] = *reinterpret_cast<ushort*>(&h0);
    nfb[row * NC + lane + 64] = *reinterpret_cast<ushort*>(&h1);
  }
}

// ==================== K2: sim = nf @ nf^T via bf16 MFMA -> adjacency words ====================
// (verified round-3 kernel, unchanged)
__global__ __launch_bounds__(256) void sim_kernel(const ushort* __restrict__ nfb,
                                                  u64* __restrict__ adj) {
  __shared__ __align__(16) ushort tA[64 * 128];
  __shared__ __align__(16) ushort tB[64 * 128];
  __shared__ u64 rowbits[64];
  int I0 = blockIdx.x * 64, J0 = blockIdx.y * 64;
  int tid = threadIdx.x;
  if (tid < 64) rowbits[tid] = 0ull;
  for (int f = tid; f < 1024; f += 256) {
    int r = f >> 4, c = f & 15;
    int scnk = c ^ (r & 7);
    *(i32x4*)&tA[r * 128 + scnk * 8] = *(const i32x4*)(nfb + (size_t)(I0 + r) * NC + c * 8);
    *(i32x4*)&tB[r * 128 + scnk * 8] = *(const i32x4*)(nfb + (size_t)(J0 + r) * NC + c * 8);
  }
  __syncthreads();
  int w = tid >> 6, l = tid & 63;
  int r = l & 15, kg = l >> 4;
  f32x4 acc[4] = {{0.f, 0.f, 0.f, 0.f}, {0.f, 0.f, 0.f, 0.f},
                  {0.f, 0.f, 0.f, 0.f}, {0.f, 0.f, 0.f, 0.f}};
  int Ar = 16 * w + r;
  #pragma unroll
  for (int kk = 0; kk < 4; ++kk) {
    int chunkA = (kk * 4 + kg) ^ (Ar & 7);
    bf16x8 a = *(bf16x8*)&tA[Ar * 128 + chunkA * 8];
    #pragma unroll
    for (int j = 0; j < 4; ++j) {
      int Bc = 16 * j + r;
      int chunkB = (kk * 4 + kg) ^ (Bc & 7);
      bf16x8 bf = *(bf16x8*)&tB[Bc * 128 + chunkB * 8];
      acc[j] = __builtin_amdgcn_mfma_f32_16x16x32_bf16(a, bf, acc[j], 0, 0, 0);
    }
  }
  #pragma unroll
  for (int q = 0; q < 4; ++q) {
    u64 m = 0ull;
    #pragma unroll
    for (int j = 0; j < 4; ++j) {
      float simv = acc[j][q];
      if ((1.0f - simv) * 0.5f < 0.2f) m |= 1ull << (16 * j + (l & 15));
    }
    if (m) atomicOr(&rowbits[16 * w + (l >> 4) * 4 + q], m);
  }
  __syncthreads();
  if (tid < 64) adj[(size_t)(I0 + tid) * 64 + blockIdx.y] = rowbits[tid];
}

// ==================== K3: fused deg + sparse agg + GEMM(+bias) + scatter ====================
// 256 blocks x 16 rows. agg computed into LDS (mega phase-C code, verified),
// then round-3 out_kernel GEMM with LDS-staged W^T.
__global__ __launch_bounds__(256) void k3_kernel(const u64* __restrict__ adj,
                                                 const float* __restrict__ feats,
                                                 const float* __restrict__ Wg,
                                                 const float* __restrict__ bg,
                                                 const int* __restrict__ sel,
                                                 float* __restrict__ out) {
  __shared__ __align__(16) float Wt[NC * 132];    // 67.6 KB, W transposed [cp][c]
  __shared__ __align__(16) float aggT[16 * 132];  // 8.4 KB
  int tid = threadIdx.x;
  int r0 = blockIdx.x * 16;
  for (int f = tid; f < NC * NC; f += 256) {
    int c = f >> 7, cp = f & 127;
    Wt[cp * 132 + c] = Wg[f];
  }
  // ---- deg-on-the-fly + sparse agg (ascending-j order, same as verified) ----
  int w = tid >> 6, lane = tid & 63;
  for (int rr = 0; rr < 4; ++rr) {
    int lrow = w * 4 + rr;
    int row = r0 + lrow;
    u64 mw = adj[(size_t)row * 64 + lane];
    int ctot = __popcll(mw);
    #pragma unroll
    for (int off = 32; off; off >>= 1) ctot += __shfl_xor(ctot, off);
    float dinv_i = 1.0f / sqrtf(fmaxf((float)ctot, 1.0f));
    float acc0 = 0.f, acc1 = 0.f;
    for (int wi = 0; wi < 64; ++wi) {
      u64 w64 = __shfl((long long)mw, wi);
      while (w64) {
        int bit = __builtin_ctzll(w64);
        w64 &= w64 - 1;
        int j = wi * 64 + bit;            // ascending j (deterministic order)
        u64 jm = adj[(size_t)j * 64 + lane];
        int cj = __popcll(jm);
        #pragma unroll
        for (int off = 32; off; off >>= 1) cj += __shfl_xor(cj, off);
        float dj = 1.0f / sqrtf(fmaxf((float)cj, 1.0f));
        acc0 += dj * feats[(size_t)j * NC + lane];
        acc1 += dj * feats[(size_t)j * NC + lane + 64];
      }
    }
    aggT[lrow * 132 + lane] = dinv_i * acc0;
    aggT[lrow * 132 + lane + 64] = dinv_i * acc1;
  }
  __syncthreads();
  // ---- GEMM: updated[row][cp] = sum_c aggT[row][c] * Wt[cp][c] + b[cp] ----
  int cp = tid & 127;
  int rsub = tid >> 7;
  float acc[8];
  float bb = bg[cp];
  #pragma unroll
  for (int q = 0; q < 8; ++q) acc[q] = bb;
  for (int c4 = 0; c4 < 32; ++c4) {
    float4 w4 = *(const float4*)&Wt[cp * 132 + c4 * 4];
    #pragma unroll
    for (int q = 0; q < 8; ++q) {
      float4 a4 = *(const float4*)&aggT[(rsub + 2 * q) * 132 + c4 * 4];
      acc[q] += a4.x * w4.x + a4.y * w4.y + a4.z * w4.z + a4.w * w4.w;
    }
  }
  #pragma unroll
  for (int q = 0; q < 8; ++q) {
    int row = r0 + rsub + 2 * q;
    int batch = row >> 8;
    int idx = sel[row];
    out[(size_t)(batch * NC + cp) * HWs + idx] = acc[q];
  }
}

extern "C" void kernel_launch(void* const* d_in, const int* in_sizes, int n_in,
                              void* d_out, int out_size, void* d_ws, size_t ws_size,
                              hipStream_t stream) {
  const float* z     = (const float*)d_in[0];
  const float* score = (const float*)d_in[1];
  const float* Wg    = (const float*)d_in[2];
  const float* bg    = (const float*)d_in[3];
  float* out = (float*)d_out;

  char* ws = (char*)d_ws;
  size_t off = 0;
  auto alloc = [&](size_t bytes) {
    void* p = ws + off;
    off = (off + bytes + 255) & ~(size_t)255;
    return p;
  };
  int* sel     = (int*)alloc(NN * sizeof(int));
  float* feats = (float*)alloc((size_t)NN * NC * sizeof(float));
  ushort* nfb  = (ushort*)alloc((size_t)NN * NC * sizeof(ushort));
  u64* adj     = (u64*)alloc((size_t)NN * 64 * sizeof(u64));

  k1_kernel<<<K1_GRID, 256, 0, stream>>>(z, score, out, sel, feats, nfb);
  sim_kernel<<<dim3(64, 64), 256, 0, stream>>>(nfb, adj);
  k3_kernel<<<256, 256, 0, stream>>>(adj, feats, Wg, bg, sel, out);
}

// Round 6
// 180.377 us; speedup vs baseline: 3.5706x; 1.6938x over previous
//
#include <hip/hip_runtime.h>
#include <hip/hip_bf16.h>

#define HWs 25600   // 160*160
#define NB 16       // batches
#define NC 128      // channels
#define NS 256      // selected per batch
#define NN 4096     // NB*NS total rows
#define N4 13107200 // NB*NC*HWs/4 float4 elements of z

// copy slice partition (exact, no tails):
// k1: 1024 blocks x 12 chunks = 3145728 f4   (24%)
// k2: 2560 blocks x  8 chunks = 5242880 f4   (40%)
// k3: 2048 blocks x  9 chunks = 4718592 f4   (36%)
#define K1_CPB 1024
#define K1_U 12
#define K2_CPB 2560
#define K2_U 8
#define K3_CPB 2048
#define K3_U 9
#define K2_BASE 3145728
#define K3_BASE 8388608

typedef __attribute__((ext_vector_type(8))) short bf16x8;
typedef __attribute__((ext_vector_type(4))) float f32x4;
typedef __attribute__((ext_vector_type(4))) int i32x4;
typedef unsigned long long u64;

// Forced-ILP block copy: U contiguous 256-f4 chunks per block; all U loads
// issued before any store (sched_barrier pins the batch -> U loads in flight).
template <int U>
__device__ __forceinline__ void copy_slice(const float4* __restrict__ zz,
                                           float4* __restrict__ oo,
                                           size_t base, int cb, int tid) {
  size_t start = base + (size_t)cb * (U * 256) + tid;
  float4 v[U];
  #pragma unroll
  for (int k = 0; k < U; ++k) v[k] = zz[start + k * 256];
  __builtin_amdgcn_sched_barrier(0);
  #pragma unroll
  for (int k = 0; k < U; ++k) oo[start + k * 256] = v[k];
}

// ==================== K1: topk (LDS radix, verified) | copy slice 1 ====================
__global__ __launch_bounds__(256) void k1_kernel(const float* __restrict__ z,
                                                 const float* __restrict__ score,
                                                 float* __restrict__ out,
                                                 int* __restrict__ sel) {
  __shared__ unsigned int vals[HWs];          // 100 KB (copy blocks don't touch it)
  __shared__ int hist[256];
  __shared__ int scan_s[256];
  __shared__ int scan_eq[256];
  __shared__ int bc_dig, bc_k;
  const int tid = threadIdx.x;
  const int bid = blockIdx.x;

  if (bid >= NB) {
    copy_slice<K1_U>((const float4*)z, (float4*)out, 0, bid - NB, tid);
    return;
  }

  int b = bid;
  const float* sc = score + (size_t)b * HWs;
  for (int i = tid; i < HWs; i += 256) vals[i] = __float_as_uint(sc[i]);
  __syncthreads();

  unsigned prefix = 0; int k = NS;
  for (int d = 3; d >= 0; --d) {
    int sh = d * 8;
    hist[tid] = 0; __syncthreads();
    unsigned maskHigh = (d == 3) ? 0u : (0xFFFFFFFFu << (sh + 8));
    for (int i = tid; i < HWs; i += 256) {
      unsigned v = vals[i];
      if ((v & maskHigh) == prefix) atomicAdd(&hist[(v >> sh) & 255], 1);
    }
    __syncthreads();
    int val = hist[255 - tid];
    scan_s[tid] = val; __syncthreads();
    for (int off = 1; off < 256; off <<= 1) {
      int a = (tid >= off) ? scan_s[tid - off] : 0;
      __syncthreads();
      scan_s[tid] += a; __syncthreads();
    }
    int q = 255 - tid;
    int Sq = scan_s[tid];          // count with digit >= q under prefix
    int before = Sq - hist[q];     // count with digit > q
    if (before < k && k <= Sq) { bc_dig = q; bc_k = k - before; }
    __syncthreads();
    prefix |= ((unsigned)bc_dig) << sh;
    k = bc_k;
    __syncthreads();
  }
  unsigned t = prefix;

  int cstart = tid * 100, cend = cstart + 100;
  int cgt = 0, ceq = 0;
  for (int i = cstart; i < cend; ++i) {
    unsigned v = vals[i];
    cgt += (v > t) ? 1 : 0;
    ceq += (v == t) ? 1 : 0;
  }
  scan_s[tid] = cgt; scan_eq[tid] = ceq; __syncthreads();
  for (int off = 1; off < 256; off <<= 1) {
    int ag = (tid >= off) ? scan_s[tid - off] : 0;
    int ae = (tid >= off) ? scan_eq[tid - off] : 0;
    __syncthreads();
    scan_s[tid] += ag; scan_eq[tid] += ae; __syncthreads();
  }
  int total_gt = scan_s[255];
  int need = NS - total_gt;
  int g = scan_s[tid] - cgt;
  int e = scan_eq[tid] - ceq;
  for (int i = cstart; i < cend; ++i) {
    unsigned v = vals[i];
    if (v > t) { sel[b * NS + g] = i; ++g; }
    else if (v == t) { if (e < need) sel[b * NS + total_gt + e] = i; ++e; }
  }
}

// ==================== K2: gather+norm (1024 blocks, verified) | copy slice 2 ====================
__global__ __launch_bounds__(256) void k2_kernel(const float* __restrict__ z,
                                                 const int* __restrict__ sel,
                                                 float* __restrict__ out,
                                                 float* __restrict__ feats,
                                                 ushort* __restrict__ nfb) {
  const int tid = threadIdx.x;
  const int bid = blockIdx.x;
  if (bid >= NN / 4) {
    copy_slice<K2_U>((const float4*)z, (float4*)out, K2_BASE, bid - NN / 4, tid);
    return;
  }
  int row = bid * 4 + (tid >> 6);
  int lane = tid & 63;
  int b = row >> 8;
  int idx = sel[row];
  const float* zb = z + (size_t)b * NC * HWs + idx;
  float v0 = zb[(size_t)lane * HWs];
  float v1 = zb[(size_t)(lane + 64) * HWs];
  float ss = v0 * v0 + v1 * v1;
  #pragma unroll
  for (int off = 32; off; off >>= 1) ss += __shfl_xor(ss, off);
  float denom = fmaxf(sqrtf(ss), 1e-12f);
  feats[row * NC + lane] = v0;
  feats[row * NC + lane + 64] = v1;
  __hip_bfloat16 h0 = __float2bfloat16(v0 / denom);
  __hip_bfloat16 h1 = __float2bfloat16(v1 / denom);
  nfb[row * NC + lane] = *reinterpret_cast<ushort*>(&h0);
  nfb[row * NC + lane + 64] = *reinterpret_cast<ushort*>(&h1);
}

// ==================== K3: sim MFMA (4096 tiles, verified) | copy slice 3 ====================
__global__ __launch_bounds__(256) void k3_kernel(const ushort* __restrict__ nfb,
                                                 const float* __restrict__ z,
                                                 float* __restrict__ out,
                                                 u64* __restrict__ adj) {
  __shared__ __align__(16) ushort tA[64 * 128];
  __shared__ __align__(16) ushort tB[64 * 128];
  __shared__ u64 rowbits[64];
  const int tid = threadIdx.x;
  const int bid = blockIdx.x;
  if (bid >= 4096) {
    copy_slice<K3_U>((const float4*)z, (float4*)out, K3_BASE, bid - 4096, tid);
    return;
  }
  int I0 = (bid & 63) * 64, J0 = (bid >> 6) * 64;
  if (tid < 64) rowbits[tid] = 0ull;
  for (int f = tid; f < 1024; f += 256) {
    int r = f >> 4, c = f & 15;
    int scnk = c ^ (r & 7);
    *(i32x4*)&tA[r * 128 + scnk * 8] = *(const i32x4*)(nfb + (size_t)(I0 + r) * NC + c * 8);
    *(i32x4*)&tB[r * 128 + scnk * 8] = *(const i32x4*)(nfb + (size_t)(J0 + r) * NC + c * 8);
  }
  __syncthreads();
  int w = tid >> 6, l = tid & 63;
  int r = l & 15, kg = l >> 4;
  f32x4 acc[4] = {{0.f, 0.f, 0.f, 0.f}, {0.f, 0.f, 0.f, 0.f},
                  {0.f, 0.f, 0.f, 0.f}, {0.f, 0.f, 0.f, 0.f}};
  int Ar = 16 * w + r;
  #pragma unroll
  for (int kk = 0; kk < 4; ++kk) {
    int chunkA = (kk * 4 + kg) ^ (Ar & 7);
    bf16x8 a = *(bf16x8*)&tA[Ar * 128 + chunkA * 8];
    #pragma unroll
    for (int j = 0; j < 4; ++j) {
      int Bc = 16 * j + r;
      int chunkB = (kk * 4 + kg) ^ (Bc & 7);
      bf16x8 bf = *(bf16x8*)&tB[Bc * 128 + chunkB * 8];
      acc[j] = __builtin_amdgcn_mfma_f32_16x16x32_bf16(a, bf, acc[j], 0, 0, 0);
    }
  }
  #pragma unroll
  for (int q = 0; q < 4; ++q) {
    u64 m = 0ull;
    #pragma unroll
    for (int j = 0; j < 4; ++j) {
      float simv = acc[j][q];
      if ((1.0f - simv) * 0.5f < 0.2f) m |= 1ull << (16 * j + (l & 15));
    }
    if (m) atomicOr(&rowbits[16 * w + (l >> 4) * 4 + q], m);
  }
  __syncthreads();
  if (tid < 64) adj[(size_t)(I0 + tid) * 64 + (bid >> 6)] = rowbits[tid];
}

// ==================== K4: fused deg + sparse agg + GEMM(+bias) + scatter ====================
__global__ __launch_bounds__(256) void k4_kernel(const u64* __restrict__ adj,
                                                 const float* __restrict__ feats,
                                                 const float* __restrict__ Wg,
                                                 const float* __restrict__ bg,
                                                 const int* __restrict__ sel,
                                                 float* __restrict__ out) {
  __shared__ __align__(16) float Wt[NC * 132];    // W transposed [cp][c]
  __shared__ __align__(16) float aggT[16 * 132];
  int tid = threadIdx.x;
  int r0 = blockIdx.x * 16;
  for (int f = tid; f < NC * NC; f += 256) {
    int c = f >> 7, cp = f & 127;
    Wt[cp * 132 + c] = Wg[f];
  }
  int w = tid >> 6, lane = tid & 63;
  for (int rr = 0; rr < 4; ++rr) {
    int lrow = w * 4 + rr;
    int row = r0 + lrow;
    u64 mw = adj[(size_t)row * 64 + lane];
    int ctot = __popcll(mw);
    #pragma unroll
    for (int off = 32; off; off >>= 1) ctot += __shfl_xor(ctot, off);
    float dinv_i = 1.0f / sqrtf(fmaxf((float)ctot, 1.0f));
    float acc0 = 0.f, acc1 = 0.f;
    for (int wi = 0; wi < 64; ++wi) {
      u64 w64 = __shfl((long long)mw, wi);
      while (w64) {
        int bit = __builtin_ctzll(w64);
        w64 &= w64 - 1;
        int j = wi * 64 + bit;            // ascending j (deterministic order)
        u64 jm = adj[(size_t)j * 64 + lane];
        int cj = __popcll(jm);
        #pragma unroll
        for (int off = 32; off; off >>= 1) cj += __shfl_xor(cj, off);
        float dj = 1.0f / sqrtf(fmaxf((float)cj, 1.0f));
        acc0 += dj * feats[(size_t)j * NC + lane];
        acc1 += dj * feats[(size_t)j * NC + lane + 64];
      }
    }
    aggT[lrow * 132 + lane] = dinv_i * acc0;
    aggT[lrow * 132 + lane + 64] = dinv_i * acc1;
  }
  __syncthreads();
  int cp = tid & 127;
  int rsub = tid >> 7;
  float acc[8];
  float bb = bg[cp];
  #pragma unroll
  for (int q = 0; q < 8; ++q) acc[q] = bb;
  for (int c4 = 0; c4 < 32; ++c4) {
    float4 w4 = *(const float4*)&Wt[cp * 132 + c4 * 4];
    #pragma unroll
    for (int q = 0; q < 8; ++q) {
      float4 a4 = *(const float4*)&aggT[(rsub + 2 * q) * 132 + c4 * 4];
      acc[q] += a4.x * w4.x + a4.y * w4.y + a4.z * w4.z + a4.w * w4.w;
    }
  }
  #pragma unroll
  for (int q = 0; q < 8; ++q) {
    int row = r0 + rsub + 2 * q;
    int batch = row >> 8;
    int idx = sel[row];
    out[(size_t)(batch * NC + cp) * HWs + idx] = acc[q];
  }
}

extern "C" void kernel_launch(void* const* d_in, const int* in_sizes, int n_in,
                              void* d_out, int out_size, void* d_ws, size_t ws_size,
                              hipStream_t stream) {
  const float* z     = (const float*)d_in[0];
  const float* score = (const float*)d_in[1];
  const float* Wg    = (const float*)d_in[2];
  const float* bg    = (const float*)d_in[3];
  float* out = (float*)d_out;

  char* ws = (char*)d_ws;
  size_t off = 0;
  auto alloc = [&](size_t bytes) {
    void* p = ws + off;
    off = (off + bytes + 255) & ~(size_t)255;
    return p;
  };
  int* sel     = (int*)alloc(NN * sizeof(int));
  float* feats = (float*)alloc((size_t)NN * NC * sizeof(float));
  ushort* nfb  = (ushort*)alloc((size_t)NN * NC * sizeof(ushort));
  u64* adj     = (u64*)alloc((size_t)NN * 64 * sizeof(u64));

  k1_kernel<<<NB + K1_CPB, 256, 0, stream>>>(z, score, out, sel);
  k2_kernel<<<NN / 4 + K2_CPB, 256, 0, stream>>>(z, sel, out, feats, nfb);
  k3_kernel<<<4096 + K3_CPB, 256, 0, stream>>>(nfb, z, out, adj);
  k4_kernel<<<256, 256, 0, stream>>>(adj, feats, Wg, bg, sel, out);
}

// Round 7
// 178.082 us; speedup vs baseline: 3.6166x; 1.0129x over previous
//
#include <hip/hip_runtime.h>
#include <hip/hip_bf16.h>

#define HWs 25600   // 160*160
#define NB 16       // batches
#define NC 128      // channels
#define NS 256      // selected per batch
#define NN 4096     // NB*NS total rows
#define N4 13107200 // NB*NC*HWs/4 float4 elements of z

// copy slice partition (exact, no tails): 8 chunks/block everywhere
// k1: 2880 blocks = 5898240 f4 (45%)   [LDS-light kernel]
// k2: 2240 blocks = 4587520 f4 (35%)   [no-LDS kernel]
// k3: 1280 blocks = 2621440 f4 (20%)   [33KB-LDS kernel, smallest share]
#define K1_CPB 2880
#define K2_CPB 2240
#define K3_CPB 1280
#define CP_U 8
#define K2_BASE 5898240
#define K3_BASE 10485760

typedef __attribute__((ext_vector_type(8))) short bf16x8;
typedef __attribute__((ext_vector_type(4))) float f32x4;
typedef __attribute__((ext_vector_type(4))) int i32x4;
typedef unsigned long long u64;

// Forced-ILP block copy: U contiguous 256-f4 chunks per block; all U loads
// issued before any store (sched_barrier pins the batch -> U loads in flight).
template <int U>
__device__ __forceinline__ void copy_slice(const float4* __restrict__ zz,
                                           float4* __restrict__ oo,
                                           size_t base, int cb, int tid) {
  size_t start = base + (size_t)cb * (U * 256) + tid;
  float4 v[U];
  #pragma unroll
  for (int k = 0; k < U; ++k) v[k] = zz[start + k * 256];
  __builtin_amdgcn_sched_barrier(0);
  #pragma unroll
  for (int k = 0; k < U; ++k) oo[start + k * 256] = v[k];
}

// ==================== K1: topk (score from L2, ~3KB LDS) | copy 45% ====================
__global__ __launch_bounds__(256) void k1_kernel(const float* __restrict__ z,
                                                 const float* __restrict__ score,
                                                 float* __restrict__ out,
                                                 int* __restrict__ sel) {
  __shared__ int hist[256];
  __shared__ int scan_s[256];
  __shared__ int scan_eq[256];
  __shared__ int bc_dig, bc_k;
  const int tid = threadIdx.x;
  const int bid = blockIdx.x;

  if (bid >= NB) {
    copy_slice<CP_U>((const float4*)z, (float4*)out, 0, bid - NB, tid);
    return;
  }

  int b = bid;
  const float* sc = score + (size_t)b * HWs;
  const float4* sc4 = (const float4*)sc;

  // ---- radix select: 4 passes of 8-bit digits, score re-read from L2 ----
  unsigned prefix = 0; int k = NS;
  for (int d = 3; d >= 0; --d) {
    int sh = d * 8;
    hist[tid] = 0; __syncthreads();
    unsigned maskHigh = (d == 3) ? 0u : (0xFFFFFFFFu << (sh + 8));
    #pragma unroll 5
    for (int i4 = 0; i4 < 25; ++i4) {       // thread covers f4 range [tid*25, tid*25+25)
      float4 f = sc4[tid * 25 + i4];
      const float* fp = (const float*)&f;
      #pragma unroll
      for (int c = 0; c < 4; ++c) {
        unsigned v = __float_as_uint(fp[c]);
        if ((v & maskHigh) == prefix) atomicAdd(&hist[(v >> sh) & 255], 1);
      }
    }
    __syncthreads();
    int val = hist[255 - tid];
    scan_s[tid] = val; __syncthreads();
    for (int off = 1; off < 256; off <<= 1) {
      int a = (tid >= off) ? scan_s[tid - off] : 0;
      __syncthreads();
      scan_s[tid] += a; __syncthreads();
    }
    int q = 255 - tid;
    int Sq = scan_s[tid];          // count with digit >= q under prefix
    int before = Sq - hist[q];     // count with digit > q
    if (before < k && k <= Sq) { bc_dig = q; bc_k = k - before; }
    __syncthreads();
    prefix |= ((unsigned)bc_dig) << sh;
    k = bc_k;
    __syncthreads();
  }
  unsigned t = prefix;

  // ---- stable compaction: all v > t, plus first (NS-#gt) v == t by index ----
  int cgt = 0, ceq = 0;
  #pragma unroll 5
  for (int i4 = 0; i4 < 25; ++i4) {
    float4 f = sc4[tid * 25 + i4];
    const float* fp = (const float*)&f;
    #pragma unroll
    for (int c = 0; c < 4; ++c) {
      unsigned v = __float_as_uint(fp[c]);
      cgt += (v > t) ? 1 : 0;
      ceq += (v == t) ? 1 : 0;
    }
  }
  scan_s[tid] = cgt; scan_eq[tid] = ceq; __syncthreads();
  for (int off = 1; off < 256; off <<= 1) {
    int ag = (tid >= off) ? scan_s[tid - off] : 0;
    int ae = (tid >= off) ? scan_eq[tid - off] : 0;
    __syncthreads();
    scan_s[tid] += ag; scan_eq[tid] += ae; __syncthreads();
  }
  int total_gt = scan_s[255];
  int need = NS - total_gt;
  int g = scan_s[tid] - cgt;
  int e = scan_eq[tid] - ceq;
  for (int i4 = 0; i4 < 25; ++i4) {        // in-order within thread -> ascending index
    float4 f = sc4[tid * 25 + i4];
    const float* fp = (const float*)&f;
    #pragma unroll
    for (int c = 0; c < 4; ++c) {
      int i = tid * 100 + i4 * 4 + c;
      unsigned v = __float_as_uint(fp[c]);
      if (v > t) { sel[b * NS + g] = i; ++g; }
      else if (v == t) { if (e < need) sel[b * NS + total_gt + e] = i; ++e; }
    }
  }
}

// ==================== K2: gather+norm (1024 blocks, no LDS) | copy 35% ====================
__global__ __launch_bounds__(256) void k2_kernel(const float* __restrict__ z,
                                                 const int* __restrict__ sel,
                                                 float* __restrict__ out,
                                                 float* __restrict__ feats,
                                                 ushort* __restrict__ nfb) {
  const int tid = threadIdx.x;
  const int bid = blockIdx.x;
  if (bid >= NN / 4) {
    copy_slice<CP_U>((const float4*)z, (float4*)out, K2_BASE, bid - NN / 4, tid);
    return;
  }
  int row = bid * 4 + (tid >> 6);
  int lane = tid & 63;
  int b = row >> 8;
  int idx = sel[row];
  const float* zb = z + (size_t)b * NC * HWs + idx;
  float v0 = zb[(size_t)lane * HWs];
  float v1 = zb[(size_t)(lane + 64) * HWs];
  float ss = v0 * v0 + v1 * v1;
  #pragma unroll
  for (int off = 32; off; off >>= 1) ss += __shfl_xor(ss, off);
  float denom = fmaxf(sqrtf(ss), 1e-12f);
  feats[row * NC + lane] = v0;
  feats[row * NC + lane + 64] = v1;
  __hip_bfloat16 h0 = __float2bfloat16(v0 / denom);
  __hip_bfloat16 h1 = __float2bfloat16(v1 / denom);
  nfb[row * NC + lane] = *reinterpret_cast<ushort*>(&h0);
  nfb[row * NC + lane + 64] = *reinterpret_cast<ushort*>(&h1);
}

// ==================== K3: sim MFMA (4096 tiles, 33KB LDS) | copy 20% ====================
__global__ __launch_bounds__(256) void k3_kernel(const ushort* __restrict__ nfb,
                                                 const float* __restrict__ z,
                                                 float* __restrict__ out,
                                                 u64* __restrict__ adj) {
  __shared__ __align__(16) ushort tA[64 * 128];
  __shared__ __align__(16) ushort tB[64 * 128];
  __shared__ u64 rowbits[64];
  const int tid = threadIdx.x;
  const int bid = blockIdx.x;
  if (bid >= 4096) {
    copy_slice<CP_U>((const float4*)z, (float4*)out, K3_BASE, bid - 4096, tid);
    return;
  }
  int I0 = (bid & 63) * 64, J0 = (bid >> 6) * 64;
  if (tid < 64) rowbits[tid] = 0ull;
  for (int f = tid; f < 1024; f += 256) {
    int r = f >> 4, c = f & 15;
    int scnk = c ^ (r & 7);
    *(i32x4*)&tA[r * 128 + scnk * 8] = *(const i32x4*)(nfb + (size_t)(I0 + r) * NC + c * 8);
    *(i32x4*)&tB[r * 128 + scnk * 8] = *(const i32x4*)(nfb + (size_t)(J0 + r) * NC + c * 8);
  }
  __syncthreads();
  int w = tid >> 6, l = tid & 63;
  int r = l & 15, kg = l >> 4;
  f32x4 acc[4] = {{0.f, 0.f, 0.f, 0.f}, {0.f, 0.f, 0.f, 0.f},
                  {0.f, 0.f, 0.f, 0.f}, {0.f, 0.f, 0.f, 0.f}};
  int Ar = 16 * w + r;
  #pragma unroll
  for (int kk = 0; kk < 4; ++kk) {
    int chunkA = (kk * 4 + kg) ^ (Ar & 7);
    bf16x8 a = *(bf16x8*)&tA[Ar * 128 + chunkA * 8];
    #pragma unroll
    for (int j = 0; j < 4; ++j) {
      int Bc = 16 * j + r;
      int chunkB = (kk * 4 + kg) ^ (Bc & 7);
      bf16x8 bf = *(bf16x8*)&tB[Bc * 128 + chunkB * 8];
      acc[j] = __builtin_amdgcn_mfma_f32_16x16x32_bf16(a, bf, acc[j], 0, 0, 0);
    }
  }
  #pragma unroll
  for (int q = 0; q < 4; ++q) {
    u64 m = 0ull;
    #pragma unroll
    for (int j = 0; j < 4; ++j) {
      float simv = acc[j][q];
      if ((1.0f - simv) * 0.5f < 0.2f) m |= 1ull << (16 * j + (l & 15));
    }
    if (m) atomicOr(&rowbits[16 * w + (l >> 4) * 4 + q], m);
  }
  __syncthreads();
  if (tid < 64) adj[(size_t)(I0 + tid) * 64 + (bid >> 6)] = rowbits[tid];
}

// ==================== K4: fused deg + sparse agg + GEMM(+bias) + scatter ====================
__global__ __launch_bounds__(256) void k4_kernel(const u64* __restrict__ adj,
                                                 const float* __restrict__ feats,
                                                 const float* __restrict__ Wg,
                                                 const float* __restrict__ bg,
                                                 const int* __restrict__ sel,
                                                 float* __restrict__ out) {
  __shared__ __align__(16) float Wt[NC * 132];    // W transposed [cp][c]
  __shared__ __align__(16) float aggT[16 * 132];
  int tid = threadIdx.x;
  int r0 = blockIdx.x * 16;
  for (int f = tid; f < NC * NC; f += 256) {
    int c = f >> 7, cp = f & 127;
    Wt[cp * 132 + c] = Wg[f];
  }
  int w = tid >> 6, lane = tid & 63;
  for (int rr = 0; rr < 4; ++rr) {
    int lrow = w * 4 + rr;
    int row = r0 + lrow;
    u64 mw = adj[(size_t)row * 64 + lane];
    int ctot = __popcll(mw);
    #pragma unroll
    for (int off = 32; off; off >>= 1) ctot += __shfl_xor(ctot, off);
    float dinv_i = 1.0f / sqrtf(fmaxf((float)ctot, 1.0f));
    float acc0 = 0.f, acc1 = 0.f;
    for (int wi = 0; wi < 64; ++wi) {
      u64 w64 = __shfl((long long)mw, wi);
      while (w64) {
        int bit = __builtin_ctzll(w64);
        w64 &= w64 - 1;
        int j = wi * 64 + bit;            // ascending j (deterministic order)
        u64 jm = adj[(size_t)j * 64 + lane];
        int cj = __popcll(jm);
        #pragma unroll
        for (int off = 32; off; off >>= 1) cj += __shfl_xor(cj, off);
        float dj = 1.0f / sqrtf(fmaxf((float)cj, 1.0f));
        acc0 += dj * feats[(size_t)j * NC + lane];
        acc1 += dj * feats[(size_t)j * NC + lane + 64];
      }
    }
    aggT[lrow * 132 + lane] = dinv_i * acc0;
    aggT[lrow * 132 + lane + 64] = dinv_i * acc1;
  }
  __syncthreads();
  int cp = tid & 127;
  int rsub = tid >> 7;
  float acc[8];
  float bb = bg[cp];
  #pragma unroll
  for (int q = 0; q < 8; ++q) acc[q] = bb;
  for (int c4 = 0; c4 < 32; ++c4) {
    float4 w4 = *(const float4*)&Wt[cp * 132 + c4 * 4];
    #pragma unroll
    for (int q = 0; q < 8; ++q) {
      float4 a4 = *(const float4*)&aggT[(rsub + 2 * q) * 132 + c4 * 4];
      acc[q] += a4.x * w4.x + a4.y * w4.y + a4.z * w4.z + a4.w * w4.w;
    }
  }
  #pragma unroll
  for (int q = 0; q < 8; ++q) {
    int row = r0 + rsub + 2 * q;
    int batch = row >> 8;
    int idx = sel[row];
    out[(size_t)(batch * NC + cp) * HWs + idx] = acc[q];
  }
}

extern "C" void kernel_launch(void* const* d_in, const int* in_sizes, int n_in,
                              void* d_out, int out_size, void* d_ws, size_t ws_size,
                              hipStream_t stream) {
  const float* z     = (const float*)d_in[0];
  const float* score = (const float*)d_in[1];
  const float* Wg    = (const float*)d_in[2];
  const float* bg    = (const float*)d_in[3];
  float* out = (float*)d_out;

  char* ws = (char*)d_ws;
  size_t off = 0;
  auto alloc = [&](size_t bytes) {
    void* p = ws + off;
    off = (off + bytes + 255) & ~(size_t)255;
    return p;
  };
  int* sel     = (int*)alloc(NN * sizeof(int));
  float* feats = (float*)alloc((size_t)NN * NC * sizeof(float));
  ushort* nfb  = (ushort*)alloc((size_t)NN * NC * sizeof(ushort));
  u64* adj     = (u64*)alloc((size_t)NN * 64 * sizeof(u64));

  k1_kernel<<<NB + K1_CPB, 256, 0, stream>>>(z, score, out, sel);
  k2_kernel<<<NN / 4 + K2_CPB, 256, 0, stream>>>(z, sel, out, feats, nfb);
  k3_kernel<<<4096 + K3_CPB, 256, 0, stream>>>(nfb, z, out, adj);
  k4_kernel<<<256, 256, 0, stream>>>(adj, feats, Wg, bg, sel, out);
}

// Round 8
// 163.979 us; speedup vs baseline: 3.9276x; 1.0860x over previous
//
#include <hip/hip_runtime.h>
#include <hip/hip_bf16.h>

#define HWs 25600   // 160*160
#define NB 16       // batches
#define NC 128      // channels
#define NS 256      // selected per batch
#define NN 4096     // NB*NS total rows
#define N4 13107200 // NB*NC*HWs/4 float4 elements of z
#define CP_U 8
#define K1_CPB 6400 // 6400 blocks x 8 chunks x 256 thr = 13107200 f4 = 100% of z

typedef __attribute__((ext_vector_type(8))) short bf16x8;
typedef __attribute__((ext_vector_type(4))) float f32x4;
typedef __attribute__((ext_vector_type(4))) int i32x4;
typedef unsigned long long u64;

// Forced-ILP block copy: U contiguous 256-f4 chunks per block; all U loads
// issued before any store (sched_barrier pins order -> U loads in flight).
// Non-temporal stores keep z resident in L3 across timed iterations.
template <int U>
__device__ __forceinline__ void copy_slice(const float4* __restrict__ zz,
                                           float4* __restrict__ oo,
                                           int cb, int tid) {
  size_t start = (size_t)cb * (U * 256) + tid;
  float4 v[U];
  #pragma unroll
  for (int k = 0; k < U; ++k) v[k] = zz[start + k * 256];
  __builtin_amdgcn_sched_barrier(0);
  #pragma unroll
  for (int k = 0; k < U; ++k)
    __builtin_nontemporal_store(*(const f32x4*)&v[k], (f32x4*)&oo[start + k * 256]);
}

// ==================== K1: topk (score from L2, ~3KB LDS) | copy 100% ====================
__global__ __launch_bounds__(256) void k1_kernel(const float* __restrict__ z,
                                                 const float* __restrict__ score,
                                                 float* __restrict__ out,
                                                 int* __restrict__ sel) {
  __shared__ int hist[256];
  __shared__ int scan_s[256];
  __shared__ int scan_eq[256];
  __shared__ int bc_dig, bc_k;
  const int tid = threadIdx.x;
  const int bid = blockIdx.x;

  if (bid >= NB) {
    copy_slice<CP_U>((const float4*)z, (float4*)out, bid - NB, tid);
    return;
  }

  int b = bid;
  const float* sc = score + (size_t)b * HWs;
  const float4* sc4 = (const float4*)sc;

  // ---- radix select: 4 passes of 8-bit digits, score re-read from L2 ----
  unsigned prefix = 0; int k = NS;
  for (int d = 3; d >= 0; --d) {
    int sh = d * 8;
    hist[tid] = 0; __syncthreads();
    unsigned maskHigh = (d == 3) ? 0u : (0xFFFFFFFFu << (sh + 8));
    #pragma unroll 5
    for (int i4 = 0; i4 < 25; ++i4) {       // thread covers f4 range [tid*25, tid*25+25)
      float4 f = sc4[tid * 25 + i4];
      const float* fp = (const float*)&f;
      #pragma unroll
      for (int c = 0; c < 4; ++c) {
        unsigned v = __float_as_uint(fp[c]);
        if ((v & maskHigh) == prefix) atomicAdd(&hist[(v >> sh) & 255], 1);
      }
    }
    __syncthreads();
    int val = hist[255 - tid];
    scan_s[tid] = val; __syncthreads();
    for (int off = 1; off < 256; off <<= 1) {
      int a = (tid >= off) ? scan_s[tid - off] : 0;
      __syncthreads();
      scan_s[tid] += a; __syncthreads();
    }
    int q = 255 - tid;
    int Sq = scan_s[tid];          // count with digit >= q under prefix
    int before = Sq - hist[q];     // count with digit > q
    if (before < k && k <= Sq) { bc_dig = q; bc_k = k - before; }
    __syncthreads();
    prefix |= ((unsigned)bc_dig) << sh;
    k = bc_k;
    __syncthreads();
  }
  unsigned t = prefix;

  // ---- stable compaction: all v > t, plus first (NS-#gt) v == t by index ----
  int cgt = 0, ceq = 0;
  #pragma unroll 5
  for (int i4 = 0; i4 < 25; ++i4) {
    float4 f = sc4[tid * 25 + i4];
    const float* fp = (const float*)&f;
    #pragma unroll
    for (int c = 0; c < 4; ++c) {
      unsigned v = __float_as_uint(fp[c]);
      cgt += (v > t) ? 1 : 0;
      ceq += (v == t) ? 1 : 0;
    }
  }
  scan_s[tid] = cgt; scan_eq[tid] = ceq; __syncthreads();
  for (int off = 1; off < 256; off <<= 1) {
    int ag = (tid >= off) ? scan_s[tid - off] : 0;
    int ae = (tid >= off) ? scan_eq[tid - off] : 0;
    __syncthreads();
    scan_s[tid] += ag; scan_eq[tid] += ae; __syncthreads();
  }
  int total_gt = scan_s[255];
  int need = NS - total_gt;
  int g = scan_s[tid] - cgt;
  int e = scan_eq[tid] - ceq;
  for (int i4 = 0; i4 < 25; ++i4) {        // in-order within thread -> ascending index
    float4 f = sc4[tid * 25 + i4];
    const float* fp = (const float*)&f;
    #pragma unroll
    for (int c = 0; c < 4; ++c) {
      int i = tid * 100 + i4 * 4 + c;
      unsigned v = __float_as_uint(fp[c]);
      if (v > t) { sel[b * NS + g] = i; ++g; }
      else if (v == t) { if (e < need) sel[b * NS + total_gt + e] = i; ++e; }
    }
  }
}

// ==================== K2: gather+norm (1024 blocks, pure) + zero deg ====================
__global__ __launch_bounds__(256) void k2_kernel(const float* __restrict__ z,
                                                 const int* __restrict__ sel,
                                                 float* __restrict__ feats,
                                                 ushort* __restrict__ nfb,
                                                 int* __restrict__ deg) {
  const int tid = threadIdx.x;
  const int bid = blockIdx.x;
  if (bid < 4) {   // zero deg[4096] (read by k3's atomicAdd next kernel)
    *(i32x4*)&deg[bid * 1024 + tid * 4] = (i32x4){0, 0, 0, 0};
  }
  int row = bid * 4 + (tid >> 6);
  int lane = tid & 63;
  int b = row >> 8;
  int idx = sel[row];
  const float* zb = z + (size_t)b * NC * HWs + idx;
  float v0 = zb[(size_t)lane * HWs];
  float v1 = zb[(size_t)(lane + 64) * HWs];
  float ss = v0 * v0 + v1 * v1;
  #pragma unroll
  for (int off = 32; off; off >>= 1) ss += __shfl_xor(ss, off);
  float denom = fmaxf(sqrtf(ss), 1e-12f);
  feats[row * NC + lane] = v0;
  feats[row * NC + lane + 64] = v1;
  __hip_bfloat16 h0 = __float2bfloat16(v0 / denom);
  __hip_bfloat16 h1 = __float2bfloat16(v1 / denom);
  nfb[row * NC + lane] = *reinterpret_cast<ushort*>(&h0);
  nfb[row * NC + lane + 64] = *reinterpret_cast<ushort*>(&h1);
}

// ==================== K3: sim MFMA (4096 tiles, pure) + fused deg ====================
__global__ __launch_bounds__(256) void k3_kernel(const ushort* __restrict__ nfb,
                                                 u64* __restrict__ adj,
                                                 int* __restrict__ deg) {
  __shared__ __align__(16) ushort tA[64 * 128];
  __shared__ __align__(16) ushort tB[64 * 128];
  __shared__ u64 rowbits[64];
  const int tid = threadIdx.x;
  const int bid = blockIdx.x;
  int I0 = (bid & 63) * 64, J0 = (bid >> 6) * 64;
  if (tid < 64) rowbits[tid] = 0ull;
  for (int f = tid; f < 1024; f += 256) {
    int r = f >> 4, c = f & 15;
    int scnk = c ^ (r & 7);
    *(i32x4*)&tA[r * 128 + scnk * 8] = *(const i32x4*)(nfb + (size_t)(I0 + r) * NC + c * 8);
    *(i32x4*)&tB[r * 128 + scnk * 8] = *(const i32x4*)(nfb + (size_t)(J0 + r) * NC + c * 8);
  }
  __syncthreads();
  int w = tid >> 6, l = tid & 63;
  int r = l & 15, kg = l >> 4;
  f32x4 acc[4] = {{0.f, 0.f, 0.f, 0.f}, {0.f, 0.f, 0.f, 0.f},
                  {0.f, 0.f, 0.f, 0.f}, {0.f, 0.f, 0.f, 0.f}};
  int Ar = 16 * w + r;
  #pragma unroll
  for (int kk = 0; kk < 4; ++kk) {
    int chunkA = (kk * 4 + kg) ^ (Ar & 7);
    bf16x8 a = *(bf16x8*)&tA[Ar * 128 + chunkA * 8];
    #pragma unroll
    for (int j = 0; j < 4; ++j) {
      int Bc = 16 * j + r;
      int chunkB = (kk * 4 + kg) ^ (Bc & 7);
      bf16x8 bf = *(bf16x8*)&tB[Bc * 128 + chunkB * 8];
      acc[j] = __builtin_amdgcn_mfma_f32_16x16x32_bf16(a, bf, acc[j], 0, 0, 0);
    }
  }
  #pragma unroll
  for (int q = 0; q < 4; ++q) {
    u64 m = 0ull;
    #pragma unroll
    for (int j = 0; j < 4; ++j) {
      float simv = acc[j][q];
      if ((1.0f - simv) * 0.5f < 0.2f) m |= 1ull << (16 * j + (l & 15));
    }
    if (m) atomicOr(&rowbits[16 * w + (l >> 4) * 4 + q], m);
  }
  __syncthreads();
  if (tid < 64) {
    u64 rb = rowbits[tid];
    adj[(size_t)(I0 + tid) * 64 + (bid >> 6)] = rb;
    atomicAdd(&deg[I0 + tid], __popcll(rb));   // int sum, deterministic
  }
}

// ==================== K4: agg (deg-based) + GEMM(+bias) + scatter ====================
__global__ __launch_bounds__(256) void k4_kernel(const u64* __restrict__ adj,
                                                 const float* __restrict__ feats,
                                                 const int* __restrict__ deg,
                                                 const float* __restrict__ Wg,
                                                 const float* __restrict__ bg,
                                                 const int* __restrict__ sel,
                                                 float* __restrict__ out) {
  __shared__ __align__(16) float Wt[NC * 132];    // W transposed [cp][c]
  __shared__ __align__(16) float aggT[16 * 132];
  int tid = threadIdx.x;
  int r0 = blockIdx.x * 16;
  for (int f = tid; f < NC * NC; f += 256) {
    int c = f >> 7, cp = f & 127;
    Wt[cp * 132 + c] = Wg[f];
  }
  int w = tid >> 6, lane = tid & 63;
  for (int rr = 0; rr < 4; ++rr) {
    int lrow = w * 4 + rr;
    int row = r0 + lrow;
    u64 mw = adj[(size_t)row * 64 + lane];
    float dinv_i = 1.0f / sqrtf(fmaxf((float)deg[row], 1.0f));
    float acc0 = 0.f, acc1 = 0.f;
    for (int wi = 0; wi < 64; ++wi) {
      u64 w64 = __shfl((long long)mw, wi);
      while (w64) {
        int bit = __builtin_ctzll(w64);
        w64 &= w64 - 1;
        int j = wi * 64 + bit;            // ascending j (deterministic order)
        float dj = 1.0f / sqrtf(fmaxf((float)deg[j], 1.0f));
        acc0 += dj * feats[(size_t)j * NC + lane];
        acc1 += dj * feats[(size_t)j * NC + lane + 64];
      }
    }
    aggT[lrow * 132 + lane] = dinv_i * acc0;
    aggT[lrow * 132 + lane + 64] = dinv_i * acc1;
  }
  __syncthreads();
  int cp = tid & 127;
  int rsub = tid >> 7;
  float acc[8];
  float bb = bg[cp];
  #pragma unroll
  for (int q = 0; q < 8; ++q) acc[q] = bb;
  for (int c4 = 0; c4 < 32; ++c4) {
    float4 w4 = *(const float4*)&Wt[cp * 132 + c4 * 4];
    #pragma unroll
    for (int q = 0; q < 8; ++q) {
      float4 a4 = *(const float4*)&aggT[(rsub + 2 * q) * 132 + c4 * 4];
      acc[q] += a4.x * w4.x + a4.y * w4.y + a4.z * w4.z + a4.w * w4.w;
    }
  }
  #pragma unroll
  for (int q = 0; q < 8; ++q) {
    int row = r0 + rsub + 2 * q;
    int batch = row >> 8;
    int idx = sel[row];
    out[(size_t)(batch * NC + cp) * HWs + idx] = acc[q];
  }
}

extern "C" void kernel_launch(void* const* d_in, const int* in_sizes, int n_in,
                              void* d_out, int out_size, void* d_ws, size_t ws_size,
                              hipStream_t stream) {
  const float* z     = (const float*)d_in[0];
  const float* score = (const float*)d_in[1];
  const float* Wg    = (const float*)d_in[2];
  const float* bg    = (const float*)d_in[3];
  float* out = (float*)d_out;

  char* ws = (char*)d_ws;
  size_t off = 0;
  auto alloc = [&](size_t bytes) {
    void* p = ws + off;
    off = (off + bytes + 255) & ~(size_t)255;
    return p;
  };
  int* sel     = (int*)alloc(NN * sizeof(int));
  float* feats = (float*)alloc((size_t)NN * NC * sizeof(float));
  ushort* nfb  = (ushort*)alloc((size_t)NN * NC * sizeof(ushort));
  u64* adj     = (u64*)alloc((size_t)NN * 64 * sizeof(u64));
  int* deg     = (int*)alloc(NN * sizeof(int));

  k1_kernel<<<NB + K1_CPB, 256, 0, stream>>>(z, score, out, sel);
  k2_kernel<<<NN / 4, 256, 0, stream>>>(z, sel, feats, nfb, deg);
  k3_kernel<<<4096, 256, 0, stream>>>(nfb, adj, deg);
  k4_kernel<<<256, 256, 0, stream>>>(adj, feats, deg, Wg, bg, sel, out);
}